// Round 11
// baseline (1656.902 us; speedup 1.0000x reference)
//
#include <hip/hip_runtime.h>
#include <hip/hip_bf16.h>
#include <math.h>

typedef __bf16 bf16_t;
typedef __bf16 bf16x8 __attribute__((ext_vector_type(8)));
typedef __bf16 bf16x2 __attribute__((ext_vector_type(2)));
typedef float f32x2 __attribute__((ext_vector_type(2)));
typedef float f32x4 __attribute__((ext_vector_type(4)));
typedef float f32x16 __attribute__((ext_vector_type(16)));

#define NEGBIG -3.0e38f

// ---------------------------------------------------------------------------
// Prep: weights transpose+convert AND input-copy+LN1, one dispatch.
// Blocks [0,20736): W [K][N] fp32 -> Wt [N][K] bf16 tiles.
// Blocks [20736,21217): xin -> x_f32, LN(xin) -> xn (4 tokens/block).
// ---------------------------------------------------------------------------
__global__ void __launch_bounds__(256) prep_k(
    const float* __restrict__ w_qkv, const float* __restrict__ w_proj,
    const float* __restrict__ w_fc1, const float* __restrict__ w_fc2,
    bf16_t* __restrict__ wt_qkv, bf16_t* __restrict__ wt_proj,
    bf16_t* __restrict__ wt_fc1, bf16_t* __restrict__ wt_fc2,
    const float* __restrict__ xin, const float* __restrict__ g,
    const float* __restrict__ b, float* __restrict__ xf,
    bf16_t* __restrict__ xnout)
{
    if (blockIdx.x >= 20736) {
        int t = (blockIdx.x - 20736) * 4 + (threadIdx.x >> 6);
        int lane = threadIdx.x & 63;
        const float* xp = xin + (size_t)t * 384;
        float v[6];
        float s = 0.f;
#pragma unroll
        for (int i = 0; i < 6; ++i) { v[i] = xp[lane + 64 * i]; s += v[i]; }
#pragma unroll
        for (int i = 0; i < 6; ++i) xf[(size_t)t * 384 + lane + 64 * i] = v[i];
        for (int off = 32; off > 0; off >>= 1) s += __shfl_xor(s, off);
        float mean = s * (1.0f / 384.0f);
        float s2 = 0.f;
#pragma unroll
        for (int i = 0; i < 6; ++i) { float d = v[i] - mean; s2 += d * d; }
        for (int off = 32; off > 0; off >>= 1) s2 += __shfl_xor(s2, off);
        float rstd = rsqrtf(s2 * (1.0f / 384.0f) + 1e-6f);
#pragma unroll
        for (int i = 0; i < 6; ++i) {
            int c = lane + 64 * i;
            xnout[(size_t)t * 384 + c] = (bf16_t)((v[i] - mean) * rstd * g[c] + b[c]);
        }
        return;
    }

    __shared__ float T[32][33];
    int t = blockIdx.x;
    int z = t / 1728, r = t % 1728;
    const float* W; bf16_t* Wt; int K, N, n0, k0;
    if (r < 432)       { W = w_qkv;  Wt = wt_qkv;  K = 384;  N = 1152; n0 = (r % 36) * 32;               k0 = (r / 36) * 32; }
    else if (r < 576)  { W = w_proj; Wt = wt_proj; K = 384;  N = 384;  int rr = r - 432;  n0 = (rr % 12) * 32; k0 = (rr / 12) * 32; }
    else if (r < 1152) { W = w_fc1;  Wt = wt_fc1;  K = 384;  N = 1536; int rr = r - 576;  n0 = (rr % 48) * 32; k0 = (rr / 48) * 32; }
    else               { W = w_fc2;  Wt = wt_fc2;  K = 1536; N = 384;  int rr = r - 1152; n0 = (rr % 12) * 32; k0 = (rr / 12) * 32; }
    const float* Wl = W + (size_t)z * K * N;
    bf16_t* Wtl = Wt + (size_t)z * K * N;
    int tx = threadIdx.x & 31, ty = threadIdx.x >> 5;   // 32 x 8
#pragma unroll
    for (int i = 0; i < 4; ++i)
        T[ty + 8 * i][tx] = Wl[(size_t)(k0 + ty + 8 * i) * N + n0 + tx];
    __syncthreads();
#pragma unroll
    for (int i = 0; i < 4; ++i)
        Wtl[(size_t)(n0 + ty + 8 * i) * K + k0 + tx] = (bf16_t)T[tx][ty + 8 * i];
}

// ---------------------------------------------------------------------------
// Residual-reduce + LayerNorm: x_new = x + sum(partials); optionally update
// x in place; LN(x_new) -> out (bf16 or fp32).
// ---------------------------------------------------------------------------
template <int NP, typename OT, bool WX>
__global__ void __launch_bounds__(256) ln_red_k(
    const float* __restrict__ x, const float* __restrict__ part,
    const float* __restrict__ g, const float* __restrict__ b,
    float* __restrict__ xupd, OT* __restrict__ out)
{
    int t = blockIdx.x * 4 + (threadIdx.x >> 6);
    int lane = threadIdx.x & 63;
    const size_t base = (size_t)t * 384;
    float v[6];
#pragma unroll
    for (int i = 0; i < 6; ++i) v[i] = x[base + lane + 64 * i];
#pragma unroll
    for (int p = 0; p < NP; ++p)
#pragma unroll
        for (int i = 0; i < 6; ++i)
            v[i] += part[(size_t)p * 738816 + base + lane + 64 * i];
    float s = 0.f;
#pragma unroll
    for (int i = 0; i < 6; ++i) {
        if (WX) xupd[base + lane + 64 * i] = v[i];
        s += v[i];
    }
    for (int off = 32; off > 0; off >>= 1) s += __shfl_xor(s, off);
    float mean = s * (1.0f / 384.0f);
    float s2 = 0.f;
#pragma unroll
    for (int i = 0; i < 6; ++i) { float d = v[i] - mean; s2 += d * d; }
    for (int off = 32; off > 0; off >>= 1) s2 += __shfl_xor(s2, off);
    float rstd = rsqrtf(s2 * (1.0f / 384.0f) + 1e-6f);
#pragma unroll
    for (int i = 0; i < 6; ++i) {
        int c = lane + 64 * i;
        out[base + c] = (OT)((v[i] - mean) * rstd * g[c] + b[c]);
    }
}

// ---------------------------------------------------------------------------
// bf16 MFMA GEMM: C[M,N] = A[M,K] * Bt[N,K]^T + bias
// 64x64 tile, 4 waves, BK=64 dbuf LDS, mfma_f32_32x32x16 core,
// DEPTH-2 register prefetch: iter i issues chunk i+2, LDS-writes chunk i+1
// (issued one full iteration earlier -> global latency covered).
// MODE 0: QKV scatter (V via LDS transpose); MODE 2: GELU -> bf16.
// ---------------------------------------------------------------------------
template <int MODE>
__global__ void __launch_bounds__(256) gemm_k(
    const bf16_t* __restrict__ A, const bf16_t* __restrict__ Bt,
    const float* __restrict__ bias, int M, int N, int K,
    bf16_t* __restrict__ outb,
    bf16_t* __restrict__ qb, bf16_t* __restrict__ kb, bf16_t* __restrict__ vtb)
{
    __shared__ alignas(16) bf16_t As[2][64][72];
    __shared__ alignas(16) bf16_t Bs[2][64][72];

    const int tid  = threadIdx.x;
    const int wave = tid >> 6, lane = tid & 63;
    const int m0 = blockIdx.y * 64, n0 = blockIdx.x * 64;
    const int rb = (wave >> 1) * 32, cb = (wave & 1) * 32;
    const int r32 = lane & 31, half = lane >> 5;
    const int h8 = half * 8;

    const int lrow = tid >> 3;         // 0..31
    const int lcol = (tid & 7) * 8;    // 0..56

    const bf16_t* pA0 = A  + (size_t)(m0 + lrow) * K + lcol;
    const bf16_t* pA1 = pA0 + (size_t)32 * K;
    const bf16_t* pB0 = Bt + (size_t)(n0 + lrow) * K + lcol;
    const bf16_t* pB1 = pB0 + (size_t)32 * K;

    f32x16 acc = {};
    bf16x8 va0[2], va1[2], vb0[2], vb1[2];

    va0[0] = *(const bf16x8*)(pA0);
    va1[0] = *(const bf16x8*)(pA1);
    vb0[0] = *(const bf16x8*)(pB0);
    vb1[0] = *(const bf16x8*)(pB1);
    if (64 < K) {
        va0[1] = *(const bf16x8*)(pA0 + 64);
        va1[1] = *(const bf16x8*)(pA1 + 64);
        vb0[1] = *(const bf16x8*)(pB0 + 64);
        vb1[1] = *(const bf16x8*)(pB1 + 64);
    }
    *(bf16x8*)(&As[0][lrow][lcol])      = va0[0];
    *(bf16x8*)(&As[0][lrow + 32][lcol]) = va1[0];
    *(bf16x8*)(&Bs[0][lrow][lcol])      = vb0[0];
    *(bf16x8*)(&Bs[0][lrow + 32][lcol]) = vb1[0];

    int cur = 0;
    int i = 0;
    for (int k0 = 0; k0 < K; k0 += 64, ++i) {
        __syncthreads();
        const int s = i & 1;
        if (k0 + 128 < K) {            // issue chunk i+2 into set s (its chunk
            va0[s] = *(const bf16x8*)(pA0 + k0 + 128);   // already LDS-written)
            va1[s] = *(const bf16x8*)(pA1 + k0 + 128);
            vb0[s] = *(const bf16x8*)(pB0 + k0 + 128);
            vb1[s] = *(const bf16x8*)(pB1 + k0 + 128);
        }
#pragma unroll
        for (int kc = 0; kc < 64; kc += 16) {
            bf16x8 a = *(const bf16x8*)(&As[cur][rb + r32][kc + h8]);
            bf16x8 b = *(const bf16x8*)(&Bs[cur][cb + r32][kc + h8]);
            acc = __builtin_amdgcn_mfma_f32_32x32x16_bf16(a, b, acc, 0, 0, 0);
        }
        if (k0 + 64 < K) {             // write chunk i+1 (set s^1, issued iter i-1)
            const int ns = s ^ 1;
            int nxt = cur ^ 1;
            *(bf16x8*)(&As[nxt][lrow][lcol])      = va0[ns];
            *(bf16x8*)(&As[nxt][lrow + 32][lcol]) = va1[ns];
            *(bf16x8*)(&Bs[nxt][lrow][lcol])      = vb0[ns];
            *(bf16x8*)(&Bs[nxt][lrow + 32][lcol]) = vb1[ns];
            cur = nxt;
        }
    }

    const int gc = n0 + cb + r32;
    const float bv = bias[gc];
    if (MODE == 2) {
#pragma unroll
        for (int reg = 0; reg < 16; ++reg) {
            int gr = m0 + rb + (reg & 3) + 8 * (reg >> 2) + 4 * half;
            if (gr >= M) continue;
            float val = acc[reg] + bv;
            float g = 0.5f * val * (1.0f + erff(val * 0.70710678118654752f));
            outb[(size_t)gr * N + gc] = (bf16_t)g;
        }
    } else {
        const int which = n0 / 384;               // block-uniform (64 | 384)
        if (which < 2) {                          // Q/K: d-contiguous stores
            const int rem = gc % 384;
            const int h = rem >> 6, d = rem & 63;
#pragma unroll
            for (int reg = 0; reg < 16; ++reg) {
                int gr = m0 + rb + (reg & 3) + 8 * (reg >> 2) + 4 * half;
                if (gr >= M) continue;
                float val = acc[reg] + bv;
                int bb = (gr >= 962) ? 1 : 0;
                int n = gr - 962 * bb;
                int bh = bb * 6 + h;
                bf16_t bvv = (bf16_t)val;
                if (which == 0) qb[((size_t)bh * 962 + n) * 64 + d] = bvv;
                else            kb[((size_t)bh * 962 + n) * 64 + d] = bvv;
            }
        } else {                                  // V: LDS transpose, row stores
            bf16_t (*T)[66] = (bf16_t (*)[66])(&As[0][0][0]);  // 64x66 fits
            const int hh = (n0 - 768) >> 6;       // head (tile = one head)
            __syncthreads();                      // K-loop LDS reads done
#pragma unroll
            for (int reg = 0; reg < 16; ++reg) {
                int rl = rb + (reg & 3) + 8 * (reg >> 2) + 4 * half;
                T[rl][cb + r32] = (bf16_t)(acc[reg] + bv);
            }
            __syncthreads();
            const int dl  = (wave << 4) + (lane >> 3);   // d row, +8 second pass
            const int ncs = (lane & 7) * 8;              // n chunk in tile
#pragma unroll
            for (int h8v = 0; h8v < 2; ++h8v) {
                int d = dl + h8v * 8;
                int ng0 = m0 + ncs;
                if (ng0 >= 1924) continue;
                bf16x8 v8;
#pragma unroll
                for (int j = 0; j < 8; ++j) v8[j] = T[ncs + j][d];
                int bb0 = (ng0 >= 962), bb7 = ((ng0 + 7) >= 962);
                if (bb0 == bb7 && ng0 + 7 < 1924) {
                    size_t off = ((size_t)(bb0 * 6 + hh) * 64 + d) * 992 + (ng0 - 962 * bb0);
                    if (bb0 == 0) {
                        *(bf16x8*)(vtb + off) = v8;      // 16B aligned
                    } else {                             // n' == 6 mod 8: dword stores
                        bf16x2* d2 = (bf16x2*)(vtb + off);
#pragma unroll
                        for (int j2 = 0; j2 < 4; ++j2) {
                            bf16x2 t2; t2[0] = v8[2 * j2]; t2[1] = v8[2 * j2 + 1];
                            d2[j2] = t2;
                        }
                    }
                } else {                                 // straddle / tail
                    for (int j = 0; j < 8; ++j) {
                        int ng = ng0 + j;
                        if (ng >= 1924) break;
                        int bb = (ng >= 962);
                        vtb[((size_t)(bb * 6 + hh) * 64 + d) * 992 + ng - 962 * bb] = v8[j];
                    }
                }
            }
        }
    }
}

// ---------------------------------------------------------------------------
// Split-K GEMM (proj / fc2): depth-2 prefetch core; per-z partial via plain
// coalesced stores; reduced by the following ln_red_k.
// ---------------------------------------------------------------------------
template <int KLEN>
__global__ void __launch_bounds__(256) gemm_sp(
    const bf16_t* __restrict__ A, int lda,
    const bf16_t* __restrict__ Bt, int ldb,
    const float* __restrict__ bias, int M, int N,
    float* __restrict__ part)
{
    __shared__ alignas(16) bf16_t As[2][64][72];
    __shared__ alignas(16) bf16_t Bs[2][64][72];

    const int tid  = threadIdx.x;
    const int wave = tid >> 6, lane = tid & 63;
    const int m0 = blockIdx.y * 64, n0 = blockIdx.x * 64;
    const int rb = (wave >> 1) * 32, cb = (wave & 1) * 32;
    const int r32 = lane & 31, half = lane >> 5;
    const int h8 = half * 8;
    const int ks = blockIdx.z * KLEN;

    const int lrow = tid >> 3;
    const int lcol = (tid & 7) * 8;

    const bf16_t* pA0 = A  + (size_t)(m0 + lrow) * lda + ks + lcol;
    const bf16_t* pA1 = pA0 + (size_t)32 * lda;
    const bf16_t* pB0 = Bt + (size_t)(n0 + lrow) * ldb + ks + lcol;
    const bf16_t* pB1 = pB0 + (size_t)32 * ldb;

    f32x16 acc = {};
    bf16x8 va0[2], va1[2], vb0[2], vb1[2];

    va0[0] = *(const bf16x8*)(pA0);
    va1[0] = *(const bf16x8*)(pA1);
    vb0[0] = *(const bf16x8*)(pB0);
    vb1[0] = *(const bf16x8*)(pB1);
    if (64 < KLEN) {
        va0[1] = *(const bf16x8*)(pA0 + 64);
        va1[1] = *(const bf16x8*)(pA1 + 64);
        vb0[1] = *(const bf16x8*)(pB0 + 64);
        vb1[1] = *(const bf16x8*)(pB1 + 64);
    }
    *(bf16x8*)(&As[0][lrow][lcol])      = va0[0];
    *(bf16x8*)(&As[0][lrow + 32][lcol]) = va1[0];
    *(bf16x8*)(&Bs[0][lrow][lcol])      = vb0[0];
    *(bf16x8*)(&Bs[0][lrow + 32][lcol]) = vb1[0];

    int cur = 0;
    int i = 0;
    for (int k0 = 0; k0 < KLEN; k0 += 64, ++i) {
        __syncthreads();
        const int s = i & 1;
        if (k0 + 128 < KLEN) {
            va0[s] = *(const bf16x8*)(pA0 + k0 + 128);
            va1[s] = *(const bf16x8*)(pA1 + k0 + 128);
            vb0[s] = *(const bf16x8*)(pB0 + k0 + 128);
            vb1[s] = *(const bf16x8*)(pB1 + k0 + 128);
        }
#pragma unroll
        for (int kc = 0; kc < 64; kc += 16) {
            bf16x8 a = *(const bf16x8*)(&As[cur][rb + r32][kc + h8]);
            bf16x8 b = *(const bf16x8*)(&Bs[cur][cb + r32][kc + h8]);
            acc = __builtin_amdgcn_mfma_f32_32x32x16_bf16(a, b, acc, 0, 0, 0);
        }
        if (k0 + 64 < KLEN) {
            const int ns = s ^ 1;
            int nxt = cur ^ 1;
            *(bf16x8*)(&As[nxt][lrow][lcol])      = va0[ns];
            *(bf16x8*)(&As[nxt][lrow + 32][lcol]) = va1[ns];
            *(bf16x8*)(&Bs[nxt][lrow][lcol])      = vb0[ns];
            *(bf16x8*)(&Bs[nxt][lrow + 32][lcol]) = vb1[ns];
            cur = nxt;
        }
    }

    const int gc = n0 + cb + r32;
    const float bv = (blockIdx.z == 0) ? bias[gc] : 0.f;
    float* pz = part + (size_t)blockIdx.z * 738816;   // 1924*384 per z-slice
#pragma unroll
    for (int reg = 0; reg < 16; ++reg) {
        int gr = m0 + rb + (reg & 3) + 8 * (reg >> 2) + 4 * half;
        if (gr >= M) continue;
        pz[(size_t)gr * N + gc] = acc[reg] + bv;
    }
}

// ---------------------------------------------------------------------------
// Fused masked attention (R8 proven body). One WG per (bh, 16-row Q tile).
// attn_save stores vectorized as f32x2 (8B-aligned: 962 even, c8 even).
// ---------------------------------------------------------------------------
__global__ void __launch_bounds__(256) attn_k(
    const bf16_t* __restrict__ qb, const bf16_t* __restrict__ kb,
    const bf16_t* __restrict__ vtb, bf16_t* __restrict__ attnout,
    float* __restrict__ attn_save)
{
    __shared__ alignas(16) bf16_t S[16][1000];

    const int tid  = threadIdx.x;
    const int wave = tid >> 6, lane = tid & 63;
    const int q4 = lane >> 4, mm = lane & 15;
    const int bh = blockIdx.y, qt = blockIdx.x;
    const int qrow0 = qt * 16;

    int qr = qrow0 + mm; if (qr > 961) qr = 961;
    const bf16_t* qptr = qb + ((size_t)bh * 962 + qr) * 64 + q4 * 8;
    bf16x8 aq0 = *(const bf16x8*)(qptr);
    bf16x8 aq1 = *(const bf16x8*)(qptr + 32);

    for (int ct = wave; ct < 61; ct += 4) {
        int kr = ct * 16 + mm; if (kr > 961) kr = 961;
        const bf16_t* kptr = kb + ((size_t)bh * 962 + kr) * 64 + q4 * 8;
        bf16x8 b0 = *(const bf16x8*)(kptr);
        bf16x8 b1 = *(const bf16x8*)(kptr + 32);
        f32x4 acc = {};
        acc = __builtin_amdgcn_mfma_f32_16x16x32_bf16(aq0, b0, acc, 0, 0, 0);
        acc = __builtin_amdgcn_mfma_f32_16x16x32_bf16(aq1, b1, acc, 0, 0, 0);
        int col = ct * 16 + mm;
#pragma unroll
        for (int r = 0; r < 4; ++r) {
            int row = q4 * 4 + r;
            if (col < 962) S[row][col] = (bf16_t)(acc[r] * 0.125f);
        }
    }
    for (int idx = tid; idx < 16 * 38; idx += 256) {
        int r = idx / 38, c = 962 + idx % 38;
        S[r][c] = (bf16_t)NEGBIG;
    }
    __syncthreads();

    const int trow = tid >> 4, ti = tid & 15;
    float e[8][8];
    float mx = NEGBIG;
#pragma unroll
    for (int t = 0; t < 8; ++t) {
        int c8 = ti * 8 + 128 * t;
        bf16x8 xv;
        if (c8 < 1000) xv = *(const bf16x8*)(&S[trow][c8]);
        else {
#pragma unroll
            for (int j = 0; j < 8; ++j) xv[j] = (bf16_t)NEGBIG;
        }
#pragma unroll
        for (int j = 0; j < 8; ++j) { e[t][j] = (float)xv[j]; mx = fmaxf(mx, e[t][j]); }
    }
#pragma unroll
    for (int off = 8; off > 0; off >>= 1) mx = fmaxf(mx, __shfl_xor(mx, off, 16));

    float sum = 0.f;
#pragma unroll
    for (int t = 0; t < 8; ++t)
#pragma unroll
    for (int j = 0; j < 8; ++j) {
        float ev = __expf(e[t][j] - mx);
        e[t][j] = ev;
        if (ev >= 0.1f) sum += ev;
    }
#pragma unroll
    for (int off = 8; off > 0; off >>= 1) sum += __shfl_xor(sum, off, 16);
    float inv = 1.0f / sum;

    int row_g = qrow0 + trow;
#pragma unroll
    for (int t = 0; t < 8; ++t) {
        int c8 = ti * 8 + 128 * t;
        if (c8 >= 1000) continue;
        bf16x8 pv;
#pragma unroll
        for (int j = 0; j < 8; ++j) {
            float pp = (e[t][j] >= 0.1f) ? e[t][j] * inv : 0.f;
            e[t][j] = pp;
            pv[j] = (bf16_t)pp;
        }
        *(bf16x8*)(&S[trow][c8]) = pv;
        if (attn_save && row_g < 962) {
            float* dst = attn_save + ((size_t)bh * 962 + row_g) * 962 + c8;
            if (c8 + 8 <= 962) {
#pragma unroll
                for (int j2 = 0; j2 < 4; ++j2) {
                    f32x2 t2; t2[0] = e[t][2 * j2]; t2[1] = e[t][2 * j2 + 1];
                    *(f32x2*)(dst + 2 * j2) = t2;
                }
            } else {
                for (int j = 0; j < 8; ++j)
                    if (c8 + j < 962) dst[j] = e[t][j];
            }
        }
    }
    __syncthreads();

    const int wc0 = wave * 16;
    f32x4 o = {};
    for (int kc = 0; kc < 31; ++kc) {
        bf16x8 pa = *(const bf16x8*)(&S[mm][kc * 32 + q4 * 8]);
        bf16x8 vb = *(const bf16x8*)(vtb + ((size_t)bh * 64 + wc0 + mm) * 992 + kc * 32 + q4 * 8);
        o = __builtin_amdgcn_mfma_f32_16x16x32_bf16(pa, vb, o, 0, 0, 0);
    }
    int b = bh / 6, h = bh % 6;
#pragma unroll
    for (int r = 0; r < 4; ++r) {
        int qrr = qrow0 + q4 * 4 + r;
        if (qrr < 962)
            attnout[((size_t)(b * 962 + qrr)) * 384 + h * 64 + wc0 + mm] = (bf16_t)o[r];
    }
}

// ---------------------------------------------------------------------------
extern "C" void kernel_launch(void* const* d_in, const int* in_sizes, int n_in,
                              void* d_out, int out_size, void* d_ws, size_t ws_size,
                              hipStream_t stream)
{
    const float* xin    = (const float*)d_in[0];
    const float* w_qkv  = (const float*)d_in[1];
    const float* b_qkv  = (const float*)d_in[2];
    const float* w_proj = (const float*)d_in[3];
    const float* b_proj = (const float*)d_in[4];
    const float* ln1g   = (const float*)d_in[5];
    const float* ln1b   = (const float*)d_in[6];
    const float* ln2g   = (const float*)d_in[7];
    const float* ln2b   = (const float*)d_in[8];
    const float* w_fc1  = (const float*)d_in[9];
    const float* b_fc1  = (const float*)d_in[10];
    const float* w_fc2  = (const float*)d_in[11];
    const float* b_fc2  = (const float*)d_in[12];
    const float* lnfg   = (const float*)d_in[13];
    const float* lnfb   = (const float*)d_in[14];

    float* feats     = (float*)d_out;
    float* attn_save = feats + 738816;   // 2*962*384

    char* p = (char*)d_ws;
    auto alloc = [&](size_t bytes) {
        char* r = p;
        p += (bytes + 255) & ~(size_t)255;
        return r;
    };
    float*  x_f32   = (float*)alloc(1924ull * 384 * 4);
    bf16_t* xn      = (bf16_t*)alloc(1984ull * 384 * 2);    // rows padded to 64x
    bf16_t* qbuf    = (bf16_t*)alloc(12ull * 962 * 64 * 2);
    bf16_t* kbuf    = (bf16_t*)alloc(12ull * 962 * 64 * 2);
    bf16_t* vtbuf   = (bf16_t*)alloc(12ull * 64 * 992 * 2);
    bf16_t* attnout = (bf16_t*)alloc(1984ull * 384 * 2);    // rows padded
    bf16_t* mlp1    = (bf16_t*)alloc(1984ull * 1536 * 2);   // rows padded
    bf16_t* wt_qkv  = (bf16_t*)alloc(12ull * 1152 * 384 * 2);
    bf16_t* wt_proj = (bf16_t*)alloc(12ull * 384 * 384 * 2);
    bf16_t* wt_fc1  = (bf16_t*)alloc(12ull * 1536 * 384 * 2);
    bf16_t* wt_fc2  = (bf16_t*)alloc(12ull * 384 * 1536 * 2);
    float*  partbuf = (float*)alloc(4ull * 1924 * 384 * 4); // split-K partials

    // prep: weights + residual copy + layer-0 LN1, single dispatch
    prep_k<<<dim3(21217), dim3(256), 0, stream>>>(
        w_qkv, w_proj, w_fc1, w_fc2, wt_qkv, wt_proj, wt_fc1, wt_fc2,
        xin, ln1g, ln1b, x_f32, xn);

    for (int l = 0; l < 12; ++l) {
        gemm_k<0><<<dim3(18, 31), dim3(256), 0, stream>>>(
            xn, wt_qkv + (size_t)l * 1152 * 384, b_qkv + l * 1152,
            1924, 1152, 384, nullptr, qbuf, kbuf, vtbuf);
        attn_k<<<dim3(61, 12), dim3(256), 0, stream>>>(
            qbuf, kbuf, vtbuf, attnout, (l == 11) ? attn_save : (float*)nullptr);
        // proj -> partials (z=2), reduced+LN2 by ln_red_k
        gemm_sp<192><<<dim3(6, 31, 2), dim3(256), 0, stream>>>(
            attnout, 384, wt_proj + (size_t)l * 384 * 384, 384, b_proj + l * 384,
            1924, 384, partbuf);
        ln_red_k<2, bf16_t, true><<<dim3(481), dim3(256), 0, stream>>>(
            x_f32, partbuf, ln2g + l * 384, ln2b + l * 384, x_f32, xn);
        gemm_k<2><<<dim3(24, 31), dim3(256), 0, stream>>>(
            xn, wt_fc1 + (size_t)l * 1536 * 384, b_fc1 + l * 1536,
            1924, 1536, 384, mlp1, nullptr, nullptr, nullptr);
        // fc2 -> partials (z=4), reduced + next-LN1 (or final LN) by ln_red_k
        gemm_sp<384><<<dim3(6, 31, 4), dim3(256), 0, stream>>>(
            mlp1, 1536, wt_fc2 + (size_t)l * 384 * 1536, 1536, b_fc2 + l * 384,
            1924, 384, partbuf);
        if (l < 11) {
            ln_red_k<4, bf16_t, true><<<dim3(481), dim3(256), 0, stream>>>(
                x_f32, partbuf, ln1g + (l + 1) * 384, ln1b + (l + 1) * 384, x_f32, xn);
        } else {
            ln_red_k<4, float, false><<<dim3(481), dim3(256), 0, stream>>>(
                x_f32, partbuf, lnfg, lnfb, x_f32, feats);
        }
    }
}

// Round 12
// 952.022 us; speedup vs baseline: 1.7404x; 1.7404x over previous
//
#include <hip/hip_runtime.h>
#include <hip/hip_bf16.h>
#include <math.h>

typedef __bf16 bf16_t;
typedef __bf16 bf16x8 __attribute__((ext_vector_type(8)));
typedef __bf16 bf16x2 __attribute__((ext_vector_type(2)));
typedef float f32x2 __attribute__((ext_vector_type(2)));
typedef float f32x4 __attribute__((ext_vector_type(4)));
typedef float f32x16 __attribute__((ext_vector_type(16)));

#define NEGBIG -3.0e38f

// ---------------------------------------------------------------------------
// Prep: weights transpose+convert AND input-copy+LN1, one dispatch.
// ---------------------------------------------------------------------------
__global__ void __launch_bounds__(256) prep_k(
    const float* __restrict__ w_qkv, const float* __restrict__ w_proj,
    const float* __restrict__ w_fc1, const float* __restrict__ w_fc2,
    bf16_t* __restrict__ wt_qkv, bf16_t* __restrict__ wt_proj,
    bf16_t* __restrict__ wt_fc1, bf16_t* __restrict__ wt_fc2,
    const float* __restrict__ xin, const float* __restrict__ g,
    const float* __restrict__ b, float* __restrict__ xf,
    bf16_t* __restrict__ xnout)
{
    if (blockIdx.x >= 20736) {
        int t = (blockIdx.x - 20736) * 4 + (threadIdx.x >> 6);
        int lane = threadIdx.x & 63;
        const float* xp = xin + (size_t)t * 384;
        float v[6];
        float s = 0.f;
#pragma unroll
        for (int i = 0; i < 6; ++i) { v[i] = xp[lane + 64 * i]; s += v[i]; }
#pragma unroll
        for (int i = 0; i < 6; ++i) xf[(size_t)t * 384 + lane + 64 * i] = v[i];
        for (int off = 32; off > 0; off >>= 1) s += __shfl_xor(s, off);
        float mean = s * (1.0f / 384.0f);
        float s2 = 0.f;
#pragma unroll
        for (int i = 0; i < 6; ++i) { float d = v[i] - mean; s2 += d * d; }
        for (int off = 32; off > 0; off >>= 1) s2 += __shfl_xor(s2, off);
        float rstd = rsqrtf(s2 * (1.0f / 384.0f) + 1e-6f);
#pragma unroll
        for (int i = 0; i < 6; ++i) {
            int c = lane + 64 * i;
            xnout[(size_t)t * 384 + c] = (bf16_t)((v[i] - mean) * rstd * g[c] + b[c]);
        }
        return;
    }

    __shared__ float T[32][33];
    int t = blockIdx.x;
    int z = t / 1728, r = t % 1728;
    const float* W; bf16_t* Wt; int K, N, n0, k0;
    if (r < 432)       { W = w_qkv;  Wt = wt_qkv;  K = 384;  N = 1152; n0 = (r % 36) * 32;               k0 = (r / 36) * 32; }
    else if (r < 576)  { W = w_proj; Wt = wt_proj; K = 384;  N = 384;  int rr = r - 432;  n0 = (rr % 12) * 32; k0 = (rr / 12) * 32; }
    else if (r < 1152) { W = w_fc1;  Wt = wt_fc1;  K = 384;  N = 1536; int rr = r - 576;  n0 = (rr % 48) * 32; k0 = (rr / 48) * 32; }
    else               { W = w_fc2;  Wt = wt_fc2;  K = 1536; N = 384;  int rr = r - 1152; n0 = (rr % 12) * 32; k0 = (rr / 12) * 32; }
    const float* Wl = W + (size_t)z * K * N;
    bf16_t* Wtl = Wt + (size_t)z * K * N;
    int tx = threadIdx.x & 31, ty = threadIdx.x >> 5;   // 32 x 8
#pragma unroll
    for (int i = 0; i < 4; ++i)
        T[ty + 8 * i][tx] = Wl[(size_t)(k0 + ty + 8 * i) * N + n0 + tx];
    __syncthreads();
#pragma unroll
    for (int i = 0; i < 4; ++i)
        Wtl[(size_t)(n0 + ty + 8 * i) * K + k0 + tx] = (bf16_t)T[tx][ty + 8 * i];
}

// ---------------------------------------------------------------------------
// Residual-reduce + LayerNorm.
// ---------------------------------------------------------------------------
template <int NP, typename OT, bool WX>
__global__ void __launch_bounds__(256) ln_red_k(
    const float* __restrict__ x, const float* __restrict__ part,
    const float* __restrict__ g, const float* __restrict__ b,
    float* __restrict__ xupd, OT* __restrict__ out)
{
    int t = blockIdx.x * 4 + (threadIdx.x >> 6);
    int lane = threadIdx.x & 63;
    const size_t base = (size_t)t * 384;
    float v[6];
#pragma unroll
    for (int i = 0; i < 6; ++i) v[i] = x[base + lane + 64 * i];
#pragma unroll
    for (int p = 0; p < NP; ++p)
#pragma unroll
        for (int i = 0; i < 6; ++i)
            v[i] += part[(size_t)p * 738816 + base + lane + 64 * i];
    float s = 0.f;
#pragma unroll
    for (int i = 0; i < 6; ++i) {
        if (WX) xupd[base + lane + 64 * i] = v[i];
        s += v[i];
    }
    for (int off = 32; off > 0; off >>= 1) s += __shfl_xor(s, off);
    float mean = s * (1.0f / 384.0f);
    float s2 = 0.f;
#pragma unroll
    for (int i = 0; i < 6; ++i) { float d = v[i] - mean; s2 += d * d; }
    for (int off = 32; off > 0; off >>= 1) s2 += __shfl_xor(s2, off);
    float rstd = rsqrtf(s2 * (1.0f / 384.0f) + 1e-6f);
#pragma unroll
    for (int i = 0; i < 6; ++i) {
        int c = lane + 64 * i;
        out[base + c] = (OT)((v[i] - mean) * rstd * g[c] + b[c]);
    }
}

// ---------------------------------------------------------------------------
// Depth-2 prefetch GEMM core as a macro-expanded fully-unrolled loop with
// NAMED register sets (rule #20: no runtime-indexed register arrays).
// Set 0 = *_0, set 1 = *_1. Iter i: issue chunk i+2 into set (i&1),
// LDS-write chunk i+1 from set ((i&1)^1).
// ---------------------------------------------------------------------------
#define GEMM_CORE_D2(KK)                                                      \
    f32x16 acc = {};                                                          \
    bf16x8 a0_0, a1_0, b0_0, b1_0, a0_1, a1_1, b0_1, b1_1;                    \
    a0_0 = *(const bf16x8*)(pA0);                                             \
    a1_0 = *(const bf16x8*)(pA1);                                             \
    b0_0 = *(const bf16x8*)(pB0);                                             \
    b1_0 = *(const bf16x8*)(pB1);                                             \
    if (64 < KK) {                                                            \
        a0_1 = *(const bf16x8*)(pA0 + 64);                                    \
        a1_1 = *(const bf16x8*)(pA1 + 64);                                    \
        b0_1 = *(const bf16x8*)(pB0 + 64);                                    \
        b1_1 = *(const bf16x8*)(pB1 + 64);                                    \
    }                                                                         \
    *(bf16x8*)(&As[0][lrow][lcol])      = a0_0;                               \
    *(bf16x8*)(&As[0][lrow + 32][lcol]) = a1_0;                               \
    *(bf16x8*)(&Bs[0][lrow][lcol])      = b0_0;                               \
    *(bf16x8*)(&Bs[0][lrow + 32][lcol]) = b1_0;                               \
    int cur = 0;                                                              \
    _Pragma("unroll")                                                         \
    for (int i = 0; i < (KK) / 64; ++i) {                                     \
        __syncthreads();                                                      \
        const int k0 = i * 64;                                                \
        if (k0 + 128 < KK) {                                                  \
            if ((i & 1) == 0) {                                               \
                a0_0 = *(const bf16x8*)(pA0 + k0 + 128);                      \
                a1_0 = *(const bf16x8*)(pA1 + k0 + 128);                      \
                b0_0 = *(const bf16x8*)(pB0 + k0 + 128);                      \
                b1_0 = *(const bf16x8*)(pB1 + k0 + 128);                      \
            } else {                                                          \
                a0_1 = *(const bf16x8*)(pA0 + k0 + 128);                      \
                a1_1 = *(const bf16x8*)(pA1 + k0 + 128);                      \
                b0_1 = *(const bf16x8*)(pB0 + k0 + 128);                      \
                b1_1 = *(const bf16x8*)(pB1 + k0 + 128);                      \
            }                                                                 \
        }                                                                     \
        _Pragma("unroll")                                                     \
        for (int kc = 0; kc < 64; kc += 16) {                                 \
            bf16x8 a = *(const bf16x8*)(&As[cur][rb + r32][kc + h8]);         \
            bf16x8 b = *(const bf16x8*)(&Bs[cur][cb + r32][kc + h8]);         \
            acc = __builtin_amdgcn_mfma_f32_32x32x16_bf16(a, b, acc, 0, 0, 0);\
        }                                                                     \
        if (k0 + 64 < KK) {                                                   \
            int nxt = cur ^ 1;                                                \
            if ((i & 1) == 0) {                                               \
                *(bf16x8*)(&As[nxt][lrow][lcol])      = a0_1;                 \
                *(bf16x8*)(&As[nxt][lrow + 32][lcol]) = a1_1;                 \
                *(bf16x8*)(&Bs[nxt][lrow][lcol])      = b0_1;                 \
                *(bf16x8*)(&Bs[nxt][lrow + 32][lcol]) = b1_1;                 \
            } else {                                                          \
                *(bf16x8*)(&As[nxt][lrow][lcol])      = a0_0;                 \
                *(bf16x8*)(&As[nxt][lrow + 32][lcol]) = a1_0;                 \
                *(bf16x8*)(&Bs[nxt][lrow][lcol])      = b0_0;                 \
                *(bf16x8*)(&Bs[nxt][lrow + 32][lcol]) = b1_0;                 \
            }                                                                 \
            cur = nxt;                                                        \
        }                                                                     \
    }

// ---------------------------------------------------------------------------
// bf16 MFMA GEMM, K=384: C[M,N] = A[M,384] * Bt[N,384]^T + bias
// MODE 0: QKV scatter (V via LDS transpose); MODE 2: GELU -> bf16.
// ---------------------------------------------------------------------------
template <int MODE>
__global__ void __launch_bounds__(256) gemm_k(
    const bf16_t* __restrict__ A, const bf16_t* __restrict__ Bt,
    const float* __restrict__ bias, int M, int N,
    bf16_t* __restrict__ outb,
    bf16_t* __restrict__ qb, bf16_t* __restrict__ kb, bf16_t* __restrict__ vtb)
{
    __shared__ alignas(16) bf16_t As[2][64][72];
    __shared__ alignas(16) bf16_t Bs[2][64][72];

    const int tid  = threadIdx.x;
    const int wave = tid >> 6, lane = tid & 63;
    const int m0 = blockIdx.y * 64, n0 = blockIdx.x * 64;
    const int rb = (wave >> 1) * 32, cb = (wave & 1) * 32;
    const int r32 = lane & 31, half = lane >> 5;
    const int h8 = half * 8;

    const int lrow = tid >> 3;         // 0..31
    const int lcol = (tid & 7) * 8;    // 0..56

    const bf16_t* pA0 = A  + (size_t)(m0 + lrow) * 384 + lcol;
    const bf16_t* pA1 = pA0 + (size_t)32 * 384;
    const bf16_t* pB0 = Bt + (size_t)(n0 + lrow) * 384 + lcol;
    const bf16_t* pB1 = pB0 + (size_t)32 * 384;

    GEMM_CORE_D2(384)

    const int gc = n0 + cb + r32;
    const float bv = bias[gc];
    if (MODE == 2) {
#pragma unroll
        for (int reg = 0; reg < 16; ++reg) {
            int gr = m0 + rb + (reg & 3) + 8 * (reg >> 2) + 4 * half;
            if (gr >= M) continue;
            float val = acc[reg] + bv;
            float g = 0.5f * val * (1.0f + erff(val * 0.70710678118654752f));
            outb[(size_t)gr * N + gc] = (bf16_t)g;
        }
    } else {
        const int which = n0 / 384;               // block-uniform (64 | 384)
        if (which < 2) {                          // Q/K: d-contiguous stores
            const int rem = gc % 384;
            const int h = rem >> 6, d = rem & 63;
#pragma unroll
            for (int reg = 0; reg < 16; ++reg) {
                int gr = m0 + rb + (reg & 3) + 8 * (reg >> 2) + 4 * half;
                if (gr >= M) continue;
                float val = acc[reg] + bv;
                int bb = (gr >= 962) ? 1 : 0;
                int n = gr - 962 * bb;
                int bh = bb * 6 + h;
                bf16_t bvv = (bf16_t)val;
                if (which == 0) qb[((size_t)bh * 962 + n) * 64 + d] = bvv;
                else            kb[((size_t)bh * 962 + n) * 64 + d] = bvv;
            }
        } else {                                  // V: LDS transpose, row stores
            bf16_t (*T)[66] = (bf16_t (*)[66])(&As[0][0][0]);  // 64x66 fits
            const int hh = (n0 - 768) >> 6;       // head (tile = one head)
            __syncthreads();                      // K-loop LDS reads done
#pragma unroll
            for (int reg = 0; reg < 16; ++reg) {
                int rl = rb + (reg & 3) + 8 * (reg >> 2) + 4 * half;
                T[rl][cb + r32] = (bf16_t)(acc[reg] + bv);
            }
            __syncthreads();
            const int dl  = (wave << 4) + (lane >> 3);   // d row, +8 second pass
            const int ncs = (lane & 7) * 8;              // n chunk in tile
#pragma unroll
            for (int h8v = 0; h8v < 2; ++h8v) {
                int d = dl + h8v * 8;
                int ng0 = m0 + ncs;
                if (ng0 >= 1924) continue;
                bf16x8 v8;
#pragma unroll
                for (int j = 0; j < 8; ++j) v8[j] = T[ncs + j][d];
                int bb0 = (ng0 >= 962), bb7 = ((ng0 + 7) >= 962);
                if (bb0 == bb7 && ng0 + 7 < 1924) {
                    size_t off = ((size_t)(bb0 * 6 + hh) * 64 + d) * 992 + (ng0 - 962 * bb0);
                    if (bb0 == 0) {
                        *(bf16x8*)(vtb + off) = v8;      // 16B aligned
                    } else {                             // n' == 6 mod 8: dword stores
                        bf16x2* d2 = (bf16x2*)(vtb + off);
#pragma unroll
                        for (int j2 = 0; j2 < 4; ++j2) {
                            bf16x2 t2; t2[0] = v8[2 * j2]; t2[1] = v8[2 * j2 + 1];
                            d2[j2] = t2;
                        }
                    }
                } else {                                 // straddle / tail
                    for (int j = 0; j < 8; ++j) {
                        int ng = ng0 + j;
                        if (ng >= 1924) break;
                        int bb = (ng >= 962);
                        vtb[((size_t)(bb * 6 + hh) * 64 + d) * 992 + ng - 962 * bb] = v8[j];
                    }
                }
            }
        }
    }
}

// ---------------------------------------------------------------------------
// Split-K GEMM (proj / fc2): depth-2 core; per-z partial via plain stores.
// ---------------------------------------------------------------------------
template <int KLEN>
__global__ void __launch_bounds__(256) gemm_sp(
    const bf16_t* __restrict__ A, int lda,
    const bf16_t* __restrict__ Bt, int ldb,
    const float* __restrict__ bias, int M, int N,
    float* __restrict__ part)
{
    __shared__ alignas(16) bf16_t As[2][64][72];
    __shared__ alignas(16) bf16_t Bs[2][64][72];

    const int tid  = threadIdx.x;
    const int wave = tid >> 6, lane = tid & 63;
    const int m0 = blockIdx.y * 64, n0 = blockIdx.x * 64;
    const int rb = (wave >> 1) * 32, cb = (wave & 1) * 32;
    const int r32 = lane & 31, half = lane >> 5;
    const int h8 = half * 8;
    const int ks = blockIdx.z * KLEN;

    const int lrow = tid >> 3;
    const int lcol = (tid & 7) * 8;

    const bf16_t* pA0 = A  + (size_t)(m0 + lrow) * lda + ks + lcol;
    const bf16_t* pA1 = pA0 + (size_t)32 * lda;
    const bf16_t* pB0 = Bt + (size_t)(n0 + lrow) * ldb + ks + lcol;
    const bf16_t* pB1 = pB0 + (size_t)32 * ldb;

    GEMM_CORE_D2(KLEN)

    const int gc = n0 + cb + r32;
    const float bv = (blockIdx.z == 0) ? bias[gc] : 0.f;
    float* pz = part + (size_t)blockIdx.z * 738816;   // 1924*384 per z-slice
#pragma unroll
    for (int reg = 0; reg < 16; ++reg) {
        int gr = m0 + rb + (reg & 3) + 8 * (reg >> 2) + 4 * half;
        if (gr >= M) continue;
        pz[(size_t)gr * N + gc] = acc[reg] + bv;
    }
}

// ---------------------------------------------------------------------------
// Fused masked attention (R8 proven body). One WG per (bh, 16-row Q tile).
// ---------------------------------------------------------------------------
__global__ void __launch_bounds__(256) attn_k(
    const bf16_t* __restrict__ qb, const bf16_t* __restrict__ kb,
    const bf16_t* __restrict__ vtb, bf16_t* __restrict__ attnout,
    float* __restrict__ attn_save)
{
    __shared__ alignas(16) bf16_t S[16][1000];

    const int tid  = threadIdx.x;
    const int wave = tid >> 6, lane = tid & 63;
    const int q4 = lane >> 4, mm = lane & 15;
    const int bh = blockIdx.y, qt = blockIdx.x;
    const int qrow0 = qt * 16;

    int qr = qrow0 + mm; if (qr > 961) qr = 961;
    const bf16_t* qptr = qb + ((size_t)bh * 962 + qr) * 64 + q4 * 8;
    bf16x8 aq0 = *(const bf16x8*)(qptr);
    bf16x8 aq1 = *(const bf16x8*)(qptr + 32);

    for (int ct = wave; ct < 61; ct += 4) {
        int kr = ct * 16 + mm; if (kr > 961) kr = 961;
        const bf16_t* kptr = kb + ((size_t)bh * 962 + kr) * 64 + q4 * 8;
        bf16x8 b0 = *(const bf16x8*)(kptr);
        bf16x8 b1 = *(const bf16x8*)(kptr + 32);
        f32x4 acc = {};
        acc = __builtin_amdgcn_mfma_f32_16x16x32_bf16(aq0, b0, acc, 0, 0, 0);
        acc = __builtin_amdgcn_mfma_f32_16x16x32_bf16(aq1, b1, acc, 0, 0, 0);
        int col = ct * 16 + mm;
#pragma unroll
        for (int r = 0; r < 4; ++r) {
            int row = q4 * 4 + r;
            if (col < 962) S[row][col] = (bf16_t)(acc[r] * 0.125f);
        }
    }
    for (int idx = tid; idx < 16 * 38; idx += 256) {
        int r = idx / 38, c = 962 + idx % 38;
        S[r][c] = (bf16_t)NEGBIG;
    }
    __syncthreads();

    const int trow = tid >> 4, ti = tid & 15;
    float e[8][8];
    float mx = NEGBIG;
#pragma unroll
    for (int t = 0; t < 8; ++t) {
        int c8 = ti * 8 + 128 * t;
        bf16x8 xv;
        if (c8 < 1000) xv = *(const bf16x8*)(&S[trow][c8]);
        else {
#pragma unroll
            for (int j = 0; j < 8; ++j) xv[j] = (bf16_t)NEGBIG;
        }
#pragma unroll
        for (int j = 0; j < 8; ++j) { e[t][j] = (float)xv[j]; mx = fmaxf(mx, e[t][j]); }
    }
#pragma unroll
    for (int off = 8; off > 0; off >>= 1) mx = fmaxf(mx, __shfl_xor(mx, off, 16));

    float sum = 0.f;
#pragma unroll
    for (int t = 0; t < 8; ++t)
#pragma unroll
    for (int j = 0; j < 8; ++j) {
        float ev = __expf(e[t][j] - mx);
        e[t][j] = ev;
        if (ev >= 0.1f) sum += ev;
    }
#pragma unroll
    for (int off = 8; off > 0; off >>= 1) sum += __shfl_xor(sum, off, 16);
    float inv = 1.0f / sum;

    int row_g = qrow0 + trow;
#pragma unroll
    for (int t = 0; t < 8; ++t) {
        int c8 = ti * 8 + 128 * t;
        if (c8 >= 1000) continue;
        bf16x8 pv;
#pragma unroll
        for (int j = 0; j < 8; ++j) {
            float pp = (e[t][j] >= 0.1f) ? e[t][j] * inv : 0.f;
            e[t][j] = pp;
            pv[j] = (bf16_t)pp;
        }
        *(bf16x8*)(&S[trow][c8]) = pv;
        if (attn_save && row_g < 962) {
            float* dst = attn_save + ((size_t)bh * 962 + row_g) * 962 + c8;
            if (c8 + 8 <= 962) {
#pragma unroll
                for (int j2 = 0; j2 < 4; ++j2) {
                    f32x2 t2; t2[0] = e[t][2 * j2]; t2[1] = e[t][2 * j2 + 1];
                    *(f32x2*)(dst + 2 * j2) = t2;
                }
            } else {
                for (int j = 0; j < 8; ++j)
                    if (c8 + j < 962) dst[j] = e[t][j];
            }
        }
    }
    __syncthreads();

    const int wc0 = wave * 16;
    f32x4 o = {};
    for (int kc = 0; kc < 31; ++kc) {
        bf16x8 pa = *(const bf16x8*)(&S[mm][kc * 32 + q4 * 8]);
        bf16x8 vb = *(const bf16x8*)(vtb + ((size_t)bh * 64 + wc0 + mm) * 992 + kc * 32 + q4 * 8);
        o = __builtin_amdgcn_mfma_f32_16x16x32_bf16(pa, vb, o, 0, 0, 0);
    }
    int b = bh / 6, h = bh % 6;
#pragma unroll
    for (int r = 0; r < 4; ++r) {
        int qrr = qrow0 + q4 * 4 + r;
        if (qrr < 962)
            attnout[((size_t)(b * 962 + qrr)) * 384 + h * 64 + wc0 + mm] = (bf16_t)o[r];
    }
}

// ---------------------------------------------------------------------------
extern "C" void kernel_launch(void* const* d_in, const int* in_sizes, int n_in,
                              void* d_out, int out_size, void* d_ws, size_t ws_size,
                              hipStream_t stream)
{
    const float* xin    = (const float*)d_in[0];
    const float* w_qkv  = (const float*)d_in[1];
    const float* b_qkv  = (const float*)d_in[2];
    const float* w_proj = (const float*)d_in[3];
    const float* b_proj = (const float*)d_in[4];
    const float* ln1g   = (const float*)d_in[5];
    const float* ln1b   = (const float*)d_in[6];
    const float* ln2g   = (const float*)d_in[7];
    const float* ln2b   = (const float*)d_in[8];
    const float* w_fc1  = (const float*)d_in[9];
    const float* b_fc1  = (const float*)d_in[10];
    const float* w_fc2  = (const float*)d_in[11];
    const float* b_fc2  = (const float*)d_in[12];
    const float* lnfg   = (const float*)d_in[13];
    const float* lnfb   = (const float*)d_in[14];

    float* feats     = (float*)d_out;
    float* attn_save = feats + 738816;   // 2*962*384

    char* p = (char*)d_ws;
    auto alloc = [&](size_t bytes) {
        char* r = p;
        p += (bytes + 255) & ~(size_t)255;
        return r;
    };
    float*  x_f32   = (float*)alloc(1924ull * 384 * 4);
    bf16_t* xn      = (bf16_t*)alloc(1984ull * 384 * 2);    // rows padded to 64x
    bf16_t* qbuf    = (bf16_t*)alloc(12ull * 962 * 64 * 2);
    bf16_t* kbuf    = (bf16_t*)alloc(12ull * 962 * 64 * 2);
    bf16_t* vtbuf   = (bf16_t*)alloc(12ull * 64 * 992 * 2);
    bf16_t* attnout = (bf16_t*)alloc(1984ull * 384 * 2);    // rows padded
    bf16_t* mlp1    = (bf16_t*)alloc(1984ull * 1536 * 2);   // rows padded
    bf16_t* wt_qkv  = (bf16_t*)alloc(12ull * 1152 * 384 * 2);
    bf16_t* wt_proj = (bf16_t*)alloc(12ull * 384 * 384 * 2);
    bf16_t* wt_fc1  = (bf16_t*)alloc(12ull * 1536 * 384 * 2);
    bf16_t* wt_fc2  = (bf16_t*)alloc(12ull * 384 * 1536 * 2);
    float*  partbuf = (float*)alloc(4ull * 1924 * 384 * 4); // split-K partials

    // prep: weights + residual copy + layer-0 LN1, single dispatch
    prep_k<<<dim3(21217), dim3(256), 0, stream>>>(
        w_qkv, w_proj, w_fc1, w_fc2, wt_qkv, wt_proj, wt_fc1, wt_fc2,
        xin, ln1g, ln1b, x_f32, xn);

    for (int l = 0; l < 12; ++l) {
        gemm_k<0><<<dim3(18, 31), dim3(256), 0, stream>>>(
            xn, wt_qkv + (size_t)l * 1152 * 384, b_qkv + l * 1152,
            1924, 1152, nullptr, qbuf, kbuf, vtbuf);
        attn_k<<<dim3(61, 12), dim3(256), 0, stream>>>(
            qbuf, kbuf, vtbuf, attnout, (l == 11) ? attn_save : (float*)nullptr);
        // proj -> partials (z=2), reduced+LN2 by ln_red_k
        gemm_sp<192><<<dim3(6, 31, 2), dim3(256), 0, stream>>>(
            attnout, 384, wt_proj + (size_t)l * 384 * 384, 384, b_proj + l * 384,
            1924, 384, partbuf);
        ln_red_k<2, bf16_t, true><<<dim3(481), dim3(256), 0, stream>>>(
            x_f32, partbuf, ln2g + l * 384, ln2b + l * 384, x_f32, xn);
        gemm_k<2><<<dim3(24, 31), dim3(256), 0, stream>>>(
            xn, wt_fc1 + (size_t)l * 1536 * 384, b_fc1 + l * 1536,
            1924, 1536, mlp1, nullptr, nullptr, nullptr);
        // fc2 -> partials (z=4), reduced + next-LN1 (or final LN) by ln_red_k
        gemm_sp<384><<<dim3(6, 31, 4), dim3(256), 0, stream>>>(
            mlp1, 1536, wt_fc2 + (size_t)l * 384 * 1536, 1536, b_fc2 + l * 384,
            1924, 384, partbuf);
        if (l < 11) {
            ln_red_k<4, bf16_t, true><<<dim3(481), dim3(256), 0, stream>>>(
                x_f32, partbuf, ln1g + (l + 1) * 384, ln1b + (l + 1) * 384, x_f32, xn);
        } else {
            ln_red_k<4, float, false><<<dim3(481), dim3(256), 0, stream>>>(
                x_f32, partbuf, lnfg, lnfb, x_f32, feats);
        }
    }
}